// Round 6
// baseline (290.867 us; speedup 1.0000x reference)
//
#include <hip/hip_runtime.h>
#include <math.h>

#define PATCH 96
#define STRIDE 48
#define NH 21
#define NW 21
#define NP (NH * NW)              // 441 patches per (b,c)
#define BATCH 8
#define CHAN 4
#define NBC (BATCH * CHAN)        // 32
#define IMG_H 1056
#define IMG_W 1056
#define NHB 44                    // 24-row half-bands
#define NCHUNK 22                 // 48-col chunks
#define NSTAT 6                   // s1, s2, gxi, gxb, gyi, gyb
#define NPIX 9216.0f
#define NGRAD 9120.0f

__device__ unsigned int g_ticket = 0;   // module-load zeroed; last block re-zeros

// ---------------------------------------------------------------------------
// Phase 1: one block per (bc, half-band). 264 active threads (of 320) own 4
// contiguous cols across 24 rows (+1 boundary row for gy). Rows processed in
// three 8-row batches with ALL 16 loads (8 float4 + 8 right-neighbor scalars)
// issued before consumption -> 3 memory round trips per wave instead of ~6.
// Boundary row load hoisted to the front. Per-chunk partials via LDS atomics.
// ---------------------------------------------------------------------------
__global__ __launch_bounds__(320, 6) void band_stats_kernel(
    const float* __restrict__ x, float* __restrict__ pf) {
  __shared__ float acc[NCHUNK * NSTAT];   // 528 B

  const int t = threadIdx.x;              // 0..319
  const int bc = blockIdx.x / NHB;
  const int hb = blockIdx.x - bc * NHB;
  const bool active = t < 264;
  const int tc = active ? t : 263;        // clamp idle lanes to a safe column
  // right-neighbor offset: +4 except at image edge (clamped -> d4==0, lands
  // in the never-read gxb of chunk 21)
  const int noff = (tc == 263) ? 3 : 4;

  const float* rowbase = x + (size_t)bc * (IMG_H * IMG_W)
                           + (size_t)(hb * 24) * IMG_W
                           + (size_t)(4 * tc);

  float s1 = 0.f, s2 = 0.f, gxi = 0.f, gxb = 0.f, gyi = 0.f, gyb = 0.f;
  const bool bnd_is_gxb = ((tc % 12) == 11);   // last quad of its chunk

  // boundary gy row (row 24 == next hb's row 0); clamp for last hb -> gyb==0
  const int r24 = (hb == NHB - 1) ? 23 : 24;
  const float4 B = *(const float4*)(rowbase + (size_t)r24 * IMG_W);

#define SUMS_GX(A, nxt)                                                  \
  do {                                                                   \
    s1 += (A).x + (A).y + (A).z + (A).w;                                 \
    s2 += (A).x * (A).x + (A).y * (A).y + (A).z * (A).z + (A).w * (A).w; \
    float d1 = (A).y - (A).x, d2 = (A).z - (A).y, d3 = (A).w - (A).z;    \
    float d4 = (nxt) - (A).w;                                            \
    gxi += d1 * d1 + d2 * d2 + d3 * d3;                                  \
    float bd = d4 * d4;                                                  \
    if (bnd_is_gxb) gxb += bd; else gxi += bd;                           \
  } while (0)

#define GY(P, Q, acc_)                                                   \
  do {                                                                   \
    float e0 = (Q).x - (P).x, e1 = (Q).y - (P).y,                        \
          e2 = (Q).z - (P).z, e3 = (Q).w - (P).w;                        \
    acc_ += e0 * e0 + e1 * e1 + e2 * e2 + e3 * e3;                       \
  } while (0)

  float4 prev;
#pragma unroll
  for (int rb = 0; rb < 3; ++rb) {
    float4 A[8];
    float nx[8];
#pragma unroll
    for (int i = 0; i < 8; ++i) {
      const float* rp = rowbase + (size_t)(rb * 8 + i) * IMG_W;
      A[i] = *(const float4*)rp;
      nx[i] = rp[noff];
    }
#pragma unroll
    for (int i = 0; i < 8; ++i) SUMS_GX(A[i], nx[i]);
    if (rb > 0) GY(prev, A[0], gyi);
#pragma unroll
    for (int i = 0; i < 7; ++i) GY(A[i], A[i + 1], gyi);
    prev = A[7];
  }
  GY(prev, B, gyb);
#undef SUMS_GX
#undef GY

  for (int i = t; i < NCHUNK * NSTAT; i += 320) acc[i] = 0.f;
  __syncthreads();
  if (active) {
    const int chunk = tc / 12;
    atomicAdd(&acc[chunk * NSTAT + 0], s1);
    atomicAdd(&acc[chunk * NSTAT + 1], s2);
    atomicAdd(&acc[chunk * NSTAT + 2], gxi);
    atomicAdd(&acc[chunk * NSTAT + 3], gxb);
    atomicAdd(&acc[chunk * NSTAT + 4], gyi);
    atomicAdd(&acc[chunk * NSTAT + 5], gyb);
  }
  __syncthreads();
  float* dst = pf + (size_t)(bc * NHB + hb) * (NCHUNK * NSTAT);
  for (int i = t; i < NCHUNK * NSTAT; i += 320) dst[i] = acc[i];
}

// ---------------------------------------------------------------------------
// Phase 2 (+ fused finalize): one block per bc. Stage 44x22x6 slab in LDS,
// combine per patch, reduce to per-bc feature means; the LAST block to finish
// (device-scope ticket) inverts cov[:12,:12] (register GJ on wave 0) and
// writes the mean Mahalanobis distance.
// ---------------------------------------------------------------------------
__global__ __launch_bounds__(512) void patch_feats_kernel(
    const float* __restrict__ pf, float* __restrict__ featsG,
    const float* __restrict__ mu0_full, const float* __restrict__ cov_full,
    float* __restrict__ out) {
  __shared__ float S[NHB * NCHUNK * NSTAT];   // 5808 floats = 23.2 KB
  __shared__ float wsum[8][3];
  __shared__ int is_last_s;
  __shared__ float feats_s[96];
  __shared__ double inv_s[12][12];
  __shared__ float dist[BATCH];

  const int bc = blockIdx.x;
  const int t = threadIdx.x;
  const float* src = pf + (size_t)bc * (NHB * NCHUNK * NSTAT);
  for (int i = t; i < NHB * NCHUNK * NSTAT; i += 512) S[i] = src[i];
  __syncthreads();

  float fmu = 0.f, fvar = 0.f, fg = 0.f;
  if (t < NP) {
    const int ph = t / NW, pw = t - ph * NW;
    const int h0 = 2 * ph;
#define AT(h, c, s) S[((h) * NCHUNK + (c)) * NSTAT + (s)]
    float S1 = 0.f, S2 = 0.f, Gx = 0.f, Gy = 0.f;
#pragma unroll
    for (int hh = 0; hh < 4; ++hh) {
      const int h = h0 + hh;
      S1 += AT(h, pw, 0) + AT(h, pw + 1, 0);
      S2 += AT(h, pw, 1) + AT(h, pw + 1, 1);
      Gx += AT(h, pw, 2) + AT(h, pw, 3) + AT(h, pw + 1, 2);
      Gy += AT(h, pw, 4) + AT(h, pw + 1, 4);
    }
#pragma unroll
    for (int hh = 0; hh < 3; ++hh) {
      const int h = h0 + hh;
      Gy += AT(h, pw, 5) + AT(h, pw + 1, 5);
    }
#undef AT
    fmu = S1 / NPIX;
    fvar = (S2 - S1 * S1 / NPIX) / (NPIX - 1.f);
    fg = sqrtf((Gx + Gy) / NGRAD);
  }
#pragma unroll
  for (int off = 32; off > 0; off >>= 1) {
    fmu += __shfl_xor(fmu, off);
    fvar += __shfl_xor(fvar, off);
    fg += __shfl_xor(fg, off);
  }
  const int wave = t >> 6;
  if ((t & 63) == 0) { wsum[wave][0] = fmu; wsum[wave][1] = fvar; wsum[wave][2] = fg; }
  __syncthreads();
  if (t == 0) {
    float m = 0.f, v = 0.f, g = 0.f;
#pragma unroll
    for (int w = 0; w < 8; ++w) { m += wsum[w][0]; v += wsum[w][1]; g += wsum[w][2]; }
    const int b = bc / CHAN, c = bc - b * CHAN;
    __hip_atomic_store(&featsG[b * 12 + 0 + c], m / (float)NP,
                       __ATOMIC_RELEASE, __HIP_MEMORY_SCOPE_AGENT);
    __hip_atomic_store(&featsG[b * 12 + 4 + c], v / (float)NP,
                       __ATOMIC_RELEASE, __HIP_MEMORY_SCOPE_AGENT);
    __hip_atomic_store(&featsG[b * 12 + 8 + c], g / (float)NP,
                       __ATOMIC_RELEASE, __HIP_MEMORY_SCOPE_AGENT);
    __threadfence();
    unsigned old = __hip_atomic_fetch_add(&g_ticket, 1u, __ATOMIC_ACQ_REL,
                                          __HIP_MEMORY_SCOPE_AGENT);
    is_last_s = (old == NBC - 1) ? 1 : 0;
    if (old == NBC - 1)
      __hip_atomic_store(&g_ticket, 0u, __ATOMIC_RELAXED,
                         __HIP_MEMORY_SCOPE_AGENT);   // reset for next launch
  }
  __syncthreads();

  if (is_last_s) {   // ALL 512 threads of the last block enter (barriers safe)
    if (t < 64) {
      feats_s[t] = __hip_atomic_load(&featsG[t], __ATOMIC_RELAXED,
                                     __HIP_MEMORY_SCOPE_AGENT);
      if (t < 32)
        feats_s[64 + t] = __hip_atomic_load(&featsG[64 + t], __ATOMIC_RELAXED,
                                            __HIP_MEMORY_SCOPE_AGENT);
      // Register-resident Gauss-Jordan: lane c<24 owns augmented column c.
      double M[12];
#pragma unroll
      for (int r = 0; r < 12; ++r) {
        double v = 0.0;
        if (t < 12) v = (double)cov_full[r * 36 + t];
        else if (t < 24) v = (t - 12 == r) ? 1.0 : 0.0;
        M[r] = v;
      }
#pragma unroll
      for (int k = 0; k < 12; ++k) {
        const double piv = __shfl(M[k], k);
        const double ip = 1.0 / piv;
        M[k] *= ip;
#pragma unroll
        for (int r = 0; r < 12; ++r) {
          if (r == k) continue;
          const double f = __shfl(M[r], k);   // old M[r][k]
          M[r] -= f * M[k];
        }
      }
      if (t >= 12 && t < 24) {
        const int j = t - 12;
#pragma unroll
        for (int r = 0; r < 12; ++r) inv_s[r][j] = M[r];
      }
    }
    __syncthreads();
    if (t < BATCH) {
      double acc = 0.0;
      double d[12];
#pragma unroll
      for (int i = 0; i < 12; ++i)
        d[i] = (double)feats_s[t * 12 + i] - (double)mu0_full[i];
#pragma unroll
      for (int i = 0; i < 12; ++i) {
        double row = 0.0;
#pragma unroll
        for (int j = 0; j < 12; ++j) row += inv_s[i][j] * d[j];
        acc += d[i] * row;
      }
      dist[t] = (float)sqrt(acc);
    }
    __syncthreads();
    if (t == 0) {
      float m = 0.f;
#pragma unroll
      for (int b = 0; b < BATCH; ++b) m += dist[b];
      out[0] = m / (float)BATCH;
    }
  }
}

extern "C" void kernel_launch(void* const* d_in, const int* in_sizes, int n_in,
                              void* d_out, int out_size, void* d_ws, size_t ws_size,
                              hipStream_t stream) {
  const float* x   = (const float*)d_in[0];
  const float* mu0 = (const float*)d_in[1];
  const float* cov = (const float*)d_in[2];
  float* out = (float*)d_out;
  float* pf     = (float*)d_ws;                               // 32*44*132 floats = 743 KB
  float* featsG = pf + (size_t)NBC * NHB * NCHUNK * NSTAT;    // 96 floats

  band_stats_kernel<<<NBC * NHB, 320, 0, stream>>>(x, pf);
  patch_feats_kernel<<<NBC, 512, 0, stream>>>(pf, featsG, mu0, cov, out);
}

// Round 7
// 244.860 us; speedup vs baseline: 1.1879x; 1.1879x over previous
//
#include <hip/hip_runtime.h>
#include <math.h>

#define PATCH 96
#define STRIDE 48
#define NH 21
#define NW 21
#define NP (NH * NW)              // 441 patches per (b,c)
#define BATCH 8
#define CHAN 4
#define NBC (BATCH * CHAN)        // 32
#define IMG_H 1056
#define IMG_W 1056
#define GROUP_ROWS 6
#define NGRP 176                  // 6-row groups per bc
#define NHB 44                    // 24-row half-bands (4 groups each)
#define NCHUNK 22                 // 48-col chunks
#define NSTAT 6                   // s1, s2, gxi, gxb, gyi(QI), gyb(QB)
#define NPIX 9216.0f
#define NGRAD 9120.0f
#define SLAB_QUADS 1848           // 7 rows * 264 float4
#define GLL_ROUNDS 5              // 5*320 = 1600 quads via global_load_lds

__device__ unsigned int g_ticket = 0;   // module-load zeroed; last block re-zeros

#define GLOAD_LDS16(g, l)                                          \
  __builtin_amdgcn_global_load_lds(                                \
      (const __attribute__((address_space(1))) void*)(g),          \
      (__attribute__((address_space(3))) void*)(l), 16, 0, 0)

// ---------------------------------------------------------------------------
// Phase 1: one block per (bc, 6-row group). Stage the 7-row slab (6 rows +
// gy-boundary row) into LDS with width-16 global_load_lds (5 full-exec wave
// rounds, all loads in flight, single vmcnt drain at the barrier), tail 248
// quads via plain copy. Compute per-chunk partials from LDS:
//   s1,s2, gxi (chunk-internal h-diffs), gxb (chunk-boundary h-diff),
//   gyi = v-diff pairs starting at slab rows 0..4, gyb = pair (5,6).
// Last group of image: boundary row clamped to row 5 -> gyb = 0 (unused).
// ---------------------------------------------------------------------------
__global__ __launch_bounds__(320) void group_stats_kernel(
    const float* __restrict__ x, float* __restrict__ pf) {
  __shared__ alignas(16) float tile[7 * IMG_W + 32];   // +32 pad for tail waves
  __shared__ float acc[NCHUNK * NSTAT];                // 528 B

  const int t = threadIdx.x;              // 0..319
  const int bc = blockIdx.x / NGRP;
  const int g = blockIdx.x - bc * NGRP;
  const bool last_g = (g == NGRP - 1);

  const float* slab = x + (size_t)bc * (IMG_H * IMG_W)
                        + (size_t)(g * GROUP_ROWS) * IMG_W;

  // ---- stage: 1848 quads; clamp row 6 -> row 5 for the last group ----
#pragma unroll
  for (int r = 0; r < GLL_ROUNDS; ++r) {
    int q = r * 320 + t;
    int qq = (last_g && q >= 6 * 264) ? q - 264 : q;
    GLOAD_LDS16(slab + (size_t)qq * 4, tile + (size_t)q * 4);
  }
  if (t < SLAB_QUADS - GLL_ROUNDS * 320) {   // tail: 248 quads, plain copy
    int q = GLL_ROUNDS * 320 + t;
    int qq = (last_g && q >= 6 * 264) ? q - 264 : q;
    *(float4*)(tile + (size_t)q * 4) = *(const float4*)(slab + (size_t)qq * 4);
  }
  for (int i = t; i < NCHUNK * NSTAT; i += 320) acc[i] = 0.f;
  __syncthreads();   // compiler emits vmcnt(0) drain before barrier

  // ---- compute from LDS: thread t<264 owns cols 4t..4t+3 ----
  float s1 = 0.f, s2 = 0.f, gxi = 0.f, gxb = 0.f, gyi = 0.f, gyb = 0.f;
  if (t < 264) {
    const int noff = (t == 263) ? 3 : 4;       // edge clamp -> d4 = 0
    const bool bnd_is_gxb = ((t % 12) == 11);  // last quad of its chunk
    const float4* T = (const float4*)tile;
    float4 A[7];
    float nx[6];
#pragma unroll
    for (int r = 0; r < 7; ++r) A[r] = T[r * 264 + t];
#pragma unroll
    for (int r = 0; r < 6; ++r) nx[r] = tile[r * IMG_W + 4 * t + noff];
#pragma unroll
    for (int r = 0; r < 6; ++r) {
      const float4 a = A[r];
      s1 += a.x + a.y + a.z + a.w;
      s2 += a.x * a.x + a.y * a.y + a.z * a.z + a.w * a.w;
      float d1 = a.y - a.x, d2 = a.z - a.y, d3 = a.w - a.z;
      float d4 = nx[r] - a.w;
      gxi += d1 * d1 + d2 * d2 + d3 * d3;
      float bd = d4 * d4;
      if (bnd_is_gxb) gxb += bd; else gxi += bd;
    }
#pragma unroll
    for (int r = 0; r < 6; ++r) {
      const float4 p = A[r], q = A[r + 1];
      float e0 = q.x - p.x, e1 = q.y - p.y, e2 = q.z - p.z, e3 = q.w - p.w;
      float gv = e0 * e0 + e1 * e1 + e2 * e2 + e3 * e3;
      if (r < 5) gyi += gv; else gyb += gv;
    }
  }
  __syncthreads();   // acc zero-init visible (done pre-compute barrier anyway)
  if (t < 264) {
    const int chunk = t / 12;
    atomicAdd(&acc[chunk * NSTAT + 0], s1);
    atomicAdd(&acc[chunk * NSTAT + 1], s2);
    atomicAdd(&acc[chunk * NSTAT + 2], gxi);
    atomicAdd(&acc[chunk * NSTAT + 3], gxb);
    atomicAdd(&acc[chunk * NSTAT + 4], gyi);
    atomicAdd(&acc[chunk * NSTAT + 5], gyb);
  }
  __syncthreads();
  float* dst = pf + (size_t)(bc * NGRP + g) * (NCHUNK * NSTAT);
  for (int i = t; i < NCHUNK * NSTAT; i += 320) dst[i] = acc[i];
}

// ---------------------------------------------------------------------------
// Phase 2 (+ fused finalize): one block per bc. Load 176 group-cells, merge
// 4 groups -> half-band on the fly:
//   QI = sum gyi(4 groups) + gyb(first 3)   (pairs starting rows 24h..24h+22)
//   QB = gyb(group 4h+3)                    (pair starting row 24h+23)
// into the 44x22x6 LDS slab; per-patch combine and per-bc feature means; the
// LAST block (device ticket) inverts cov[:12,:12] and writes the result.
// ---------------------------------------------------------------------------
__global__ __launch_bounds__(512) void patch_feats_kernel(
    const float* __restrict__ pf, float* __restrict__ featsG,
    const float* __restrict__ mu0_full, const float* __restrict__ cov_full,
    float* __restrict__ out) {
  __shared__ float S[NHB * NCHUNK * NSTAT];   // 23.2 KB
  __shared__ float wsum[8][3];
  __shared__ int is_last_s;
  __shared__ float feats_s[96];
  __shared__ double inv_s[12][12];
  __shared__ float dist[BATCH];

  const int bc = blockIdx.x;
  const int t = threadIdx.x;
  const float* src = pf + (size_t)bc * NGRP * (NCHUNK * NSTAT);

  for (int cell = t; cell < NHB * NCHUNK; cell += 512) {
    const int h = cell / NCHUNK, c = cell - h * NCHUNK;
    const float* p0 = src + ((size_t)(4 * h) * NCHUNK + c) * NSTAT;
    float a0 = 0.f, a1 = 0.f, a2 = 0.f, a3 = 0.f, qi = 0.f, qb = 0.f;
#pragma unroll
    for (int k = 0; k < 4; ++k) {
      const float* p = p0 + (size_t)k * (NCHUNK * NSTAT);
      a0 += p[0]; a1 += p[1]; a2 += p[2]; a3 += p[3];
      qi += p[4];
      if (k < 3) qi += p[5]; else qb = p[5];
    }
    float* d = &S[cell * NSTAT];
    d[0] = a0; d[1] = a1; d[2] = a2; d[3] = a3; d[4] = qi; d[5] = qb;
  }
  __syncthreads();

  float fmu = 0.f, fvar = 0.f, fg = 0.f;
  if (t < NP) {
    const int ph = t / NW, pw = t - ph * NW;
    const int h0 = 2 * ph;
#define AT(h, c, s) S[((h) * NCHUNK + (c)) * NSTAT + (s)]
    float S1 = 0.f, S2 = 0.f, Gx = 0.f, Gy = 0.f;
#pragma unroll
    for (int hh = 0; hh < 4; ++hh) {
      const int h = h0 + hh;
      S1 += AT(h, pw, 0) + AT(h, pw + 1, 0);
      S2 += AT(h, pw, 1) + AT(h, pw + 1, 1);
      Gx += AT(h, pw, 2) + AT(h, pw, 3) + AT(h, pw + 1, 2);
      Gy += AT(h, pw, 4) + AT(h, pw + 1, 4);
    }
#pragma unroll
    for (int hh = 0; hh < 3; ++hh) {
      const int h = h0 + hh;
      Gy += AT(h, pw, 5) + AT(h, pw + 1, 5);
    }
#undef AT
    fmu = S1 / NPIX;
    fvar = (S2 - S1 * S1 / NPIX) / (NPIX - 1.f);
    fg = sqrtf((Gx + Gy) / NGRAD);
  }
#pragma unroll
  for (int off = 32; off > 0; off >>= 1) {
    fmu += __shfl_xor(fmu, off);
    fvar += __shfl_xor(fvar, off);
    fg += __shfl_xor(fg, off);
  }
  const int wave = t >> 6;
  if ((t & 63) == 0) { wsum[wave][0] = fmu; wsum[wave][1] = fvar; wsum[wave][2] = fg; }
  __syncthreads();
  if (t == 0) {
    float m = 0.f, v = 0.f, g2 = 0.f;
#pragma unroll
    for (int w = 0; w < 8; ++w) { m += wsum[w][0]; v += wsum[w][1]; g2 += wsum[w][2]; }
    const int b = bc / CHAN, c = bc - b * CHAN;
    __hip_atomic_store(&featsG[b * 12 + 0 + c], m / (float)NP,
                       __ATOMIC_RELEASE, __HIP_MEMORY_SCOPE_AGENT);
    __hip_atomic_store(&featsG[b * 12 + 4 + c], v / (float)NP,
                       __ATOMIC_RELEASE, __HIP_MEMORY_SCOPE_AGENT);
    __hip_atomic_store(&featsG[b * 12 + 8 + c], g2 / (float)NP,
                       __ATOMIC_RELEASE, __HIP_MEMORY_SCOPE_AGENT);
    __threadfence();
    unsigned old = __hip_atomic_fetch_add(&g_ticket, 1u, __ATOMIC_ACQ_REL,
                                          __HIP_MEMORY_SCOPE_AGENT);
    is_last_s = (old == NBC - 1) ? 1 : 0;
    if (old == NBC - 1)
      __hip_atomic_store(&g_ticket, 0u, __ATOMIC_RELAXED,
                         __HIP_MEMORY_SCOPE_AGENT);   // reset for next launch
  }
  __syncthreads();

  if (is_last_s) {   // all 512 threads of the last block enter (barriers safe)
    if (t < 64) {
      feats_s[t] = __hip_atomic_load(&featsG[t], __ATOMIC_RELAXED,
                                     __HIP_MEMORY_SCOPE_AGENT);
      if (t < 32)
        feats_s[64 + t] = __hip_atomic_load(&featsG[64 + t], __ATOMIC_RELAXED,
                                            __HIP_MEMORY_SCOPE_AGENT);
      // Register-resident Gauss-Jordan: lane c<24 owns augmented column c.
      double M[12];
#pragma unroll
      for (int r = 0; r < 12; ++r) {
        double v = 0.0;
        if (t < 12) v = (double)cov_full[r * 36 + t];
        else if (t < 24) v = (t - 12 == r) ? 1.0 : 0.0;
        M[r] = v;
      }
#pragma unroll
      for (int k = 0; k < 12; ++k) {
        const double piv = __shfl(M[k], k);
        const double ip = 1.0 / piv;
        M[k] *= ip;
#pragma unroll
        for (int r = 0; r < 12; ++r) {
          if (r == k) continue;
          const double f = __shfl(M[r], k);   // old M[r][k]
          M[r] -= f * M[k];
        }
      }
      if (t >= 12 && t < 24) {
        const int j = t - 12;
#pragma unroll
        for (int r = 0; r < 12; ++r) inv_s[r][j] = M[r];
      }
    }
    __syncthreads();
    if (t < BATCH) {
      double acc2 = 0.0;
      double d[12];
#pragma unroll
      for (int i = 0; i < 12; ++i)
        d[i] = (double)feats_s[t * 12 + i] - (double)mu0_full[i];
#pragma unroll
      for (int i = 0; i < 12; ++i) {
        double row = 0.0;
#pragma unroll
        for (int j = 0; j < 12; ++j) row += inv_s[i][j] * d[j];
        acc2 += d[i] * row;
      }
      dist[t] = (float)sqrt(acc2);
    }
    __syncthreads();
    if (t == 0) {
      float m = 0.f;
#pragma unroll
      for (int b = 0; b < BATCH; ++b) m += dist[b];
      out[0] = m / (float)BATCH;
    }
  }
}

extern "C" void kernel_launch(void* const* d_in, const int* in_sizes, int n_in,
                              void* d_out, int out_size, void* d_ws, size_t ws_size,
                              hipStream_t stream) {
  const float* x   = (const float*)d_in[0];
  const float* mu0 = (const float*)d_in[1];
  const float* cov = (const float*)d_in[2];
  float* out = (float*)d_out;
  float* pf     = (float*)d_ws;                               // 32*176*132 floats = 2.97 MB
  float* featsG = pf + (size_t)NBC * NGRP * NCHUNK * NSTAT;   // 96 floats

  group_stats_kernel<<<NBC * NGRP, 320, 0, stream>>>(x, pf);
  patch_feats_kernel<<<NBC, 512, 0, stream>>>(pf, featsG, mu0, cov, out);
}

// Round 8
// 226.275 us; speedup vs baseline: 1.2855x; 1.0821x over previous
//
#include <hip/hip_runtime.h>
#include <math.h>

#define PATCH 96
#define STRIDE 48
#define NH 21
#define NW 21
#define NP (NH * NW)              // 441 patches per (b,c)
#define BATCH 8
#define CHAN 4
#define NBC (BATCH * CHAN)        // 32
#define IMG_H 1056
#define IMG_W 1056
#define NHB 44                    // 24-row half-bands
#define NCHUNK 22                 // 48-col chunks
#define NSTAT 6                   // s1, s2, gxi, gxb, gyi, gyb
#define NPIX 9216.0f
#define NGRAD 9120.0f

__device__ unsigned int g_ticket = 0;   // module-load zeroed; last block re-zeros

// ---------------------------------------------------------------------------
// Phase 1 (R5's empirically-best variant, unchanged): one block per
// (bc, half-band). 264 active threads (of 320) own 4 contiguous cols across
// 24 rows (+1 boundary row for gy). Plain float4 load + one overlapping
// scalar load for the right gx neighbor (L1 hit). Per-chunk partials via LDS
// atomics; 132 floats per block.
//   gxi: horizontal diffs internal to chunk; gxb: boundary diff chunk m->m+1
//   gyi: 23 vertical pairs inside the half-band; gyb: boundary pair to the
//        first row of the next half-band (absent for hb==43)
// NOTE: do NOT batch loads into arrays (R6: spills at low VGPR cap) and do
// NOT add __launch_bounds__ min-waves (R6: 40-VGPR cap -> scratch traffic).
// ---------------------------------------------------------------------------
__global__ __launch_bounds__(320) void band_stats_kernel(
    const float* __restrict__ x, float* __restrict__ pf) {
  __shared__ float acc[NCHUNK * NSTAT];   // 528 B

  const int t = threadIdx.x;              // 0..319
  const int bc = blockIdx.x / NHB;
  const int hb = blockIdx.x - bc * NHB;
  const bool active = t < 264;
  const int tc = active ? t : 263;        // clamp idle lanes to a safe column
  // right-neighbor offset: +4 except at image edge (clamped -> d4==0, lands
  // in the never-read gxb of chunk 21)
  const int noff = (tc == 263) ? 3 : 4;

  const float* rowbase = x + (size_t)bc * (IMG_H * IMG_W)
                           + (size_t)(hb * 24) * IMG_W
                           + (size_t)(4 * tc);

  float s1 = 0.f, s2 = 0.f, gxi = 0.f, gxb = 0.f, gyi = 0.f, gyb = 0.f;
  const bool bnd_is_gxb = ((tc % 12) == 11);   // last quad of its chunk

#define SUMS_GX(A, nxt)                                                  \
  do {                                                                   \
    s1 += (A).x + (A).y + (A).z + (A).w;                                 \
    s2 += (A).x * (A).x + (A).y * (A).y + (A).z * (A).z + (A).w * (A).w; \
    float d1 = (A).y - (A).x, d2 = (A).z - (A).y, d3 = (A).w - (A).z;    \
    float d4 = (nxt) - (A).w;                                            \
    gxi += d1 * d1 + d2 * d2 + d3 * d3;                                  \
    float bd = d4 * d4;                                                  \
    if (bnd_is_gxb) gxb += bd; else gxi += bd;                           \
  } while (0)

  float4 prev;
  {  // row 0 (no gy)
    const float4 A = *(const float4*)rowbase;
    const float nxt = rowbase[noff];
    SUMS_GX(A, nxt);
    prev = A;
  }
#pragma unroll 4
  for (int r = 1; r < 24; ++r) {
    const float4 A = *(const float4*)(rowbase + (size_t)r * IMG_W);
    const float nxt = rowbase[(size_t)r * IMG_W + noff];
    SUMS_GX(A, nxt);
    const float e0 = A.x - prev.x, e1 = A.y - prev.y,
                e2 = A.z - prev.z, e3 = A.w - prev.w;
    gyi += e0 * e0 + e1 * e1 + e2 * e2 + e3 * e3;
    prev = A;
  }
  if (hb != NHB - 1) {   // boundary gy pair (row 23 <-> row 24 == next hb's row 0)
    const float4 A = *(const float4*)(rowbase + (size_t)24 * IMG_W);
    const float e0 = A.x - prev.x, e1 = A.y - prev.y,
                e2 = A.z - prev.z, e3 = A.w - prev.w;
    gyb = e0 * e0 + e1 * e1 + e2 * e2 + e3 * e3;
  }
#undef SUMS_GX

  for (int i = t; i < NCHUNK * NSTAT; i += 320) acc[i] = 0.f;
  __syncthreads();
  if (active) {
    const int chunk = tc / 12;
    atomicAdd(&acc[chunk * NSTAT + 0], s1);
    atomicAdd(&acc[chunk * NSTAT + 1], s2);
    atomicAdd(&acc[chunk * NSTAT + 2], gxi);
    atomicAdd(&acc[chunk * NSTAT + 3], gxb);
    atomicAdd(&acc[chunk * NSTAT + 4], gyi);
    atomicAdd(&acc[chunk * NSTAT + 5], gyb);
  }
  __syncthreads();
  float* dst = pf + (size_t)(bc * NHB + hb) * (NCHUNK * NSTAT);
  for (int i = t; i < NCHUNK * NSTAT; i += 320) dst[i] = acc[i];
}

// ---------------------------------------------------------------------------
// Phase 2 (+ fused finalize, R6-proven): one block per bc. Stage the bc's
// 44x22x6 slab in LDS; thread p<441 combines its 4 half-bands x 2 chunks into
// (mu, var, gmag); block-reduce to per-bc means. The LAST block to finish
// (device-scope ticket) inverts cov[:12,:12] (register GJ, one wave) and
// writes the mean Mahalanobis distance.
// ---------------------------------------------------------------------------
__global__ __launch_bounds__(512) void patch_feats_kernel(
    const float* __restrict__ pf, float* __restrict__ featsG,
    const float* __restrict__ mu0_full, const float* __restrict__ cov_full,
    float* __restrict__ out) {
  __shared__ float S[NHB * NCHUNK * NSTAT];   // 5808 floats = 23.2 KB
  __shared__ float wsum[8][3];
  __shared__ int is_last_s;
  __shared__ float feats_s[96];
  __shared__ double inv_s[12][12];
  __shared__ float dist[BATCH];

  const int bc = blockIdx.x;
  const int t = threadIdx.x;
  const float* src = pf + (size_t)bc * (NHB * NCHUNK * NSTAT);
  for (int i = t; i < NHB * NCHUNK * NSTAT; i += 512) S[i] = src[i];
  __syncthreads();

  float fmu = 0.f, fvar = 0.f, fg = 0.f;
  if (t < NP) {
    const int ph = t / NW, pw = t - ph * NW;
    const int h0 = 2 * ph;
#define AT(h, c, s) S[((h) * NCHUNK + (c)) * NSTAT + (s)]
    float S1 = 0.f, S2 = 0.f, Gx = 0.f, Gy = 0.f;
#pragma unroll
    for (int hh = 0; hh < 4; ++hh) {
      const int h = h0 + hh;
      S1 += AT(h, pw, 0) + AT(h, pw + 1, 0);
      S2 += AT(h, pw, 1) + AT(h, pw + 1, 1);
      Gx += AT(h, pw, 2) + AT(h, pw, 3) + AT(h, pw + 1, 2);
      Gy += AT(h, pw, 4) + AT(h, pw + 1, 4);
    }
#pragma unroll
    for (int hh = 0; hh < 3; ++hh) {
      const int h = h0 + hh;
      Gy += AT(h, pw, 5) + AT(h, pw + 1, 5);
    }
#undef AT
    fmu = S1 / NPIX;
    fvar = (S2 - S1 * S1 / NPIX) / (NPIX - 1.f);
    fg = sqrtf((Gx + Gy) / NGRAD);
  }
#pragma unroll
  for (int off = 32; off > 0; off >>= 1) {
    fmu += __shfl_xor(fmu, off);
    fvar += __shfl_xor(fvar, off);
    fg += __shfl_xor(fg, off);
  }
  const int wave = t >> 6;
  if ((t & 63) == 0) { wsum[wave][0] = fmu; wsum[wave][1] = fvar; wsum[wave][2] = fg; }
  __syncthreads();
  if (t == 0) {
    float m = 0.f, v = 0.f, g2 = 0.f;
#pragma unroll
    for (int w = 0; w < 8; ++w) { m += wsum[w][0]; v += wsum[w][1]; g2 += wsum[w][2]; }
    const int b = bc / CHAN, c = bc - b * CHAN;
    __hip_atomic_store(&featsG[b * 12 + 0 + c], m / (float)NP,
                       __ATOMIC_RELEASE, __HIP_MEMORY_SCOPE_AGENT);
    __hip_atomic_store(&featsG[b * 12 + 4 + c], v / (float)NP,
                       __ATOMIC_RELEASE, __HIP_MEMORY_SCOPE_AGENT);
    __hip_atomic_store(&featsG[b * 12 + 8 + c], g2 / (float)NP,
                       __ATOMIC_RELEASE, __HIP_MEMORY_SCOPE_AGENT);
    __threadfence();
    unsigned old = __hip_atomic_fetch_add(&g_ticket, 1u, __ATOMIC_ACQ_REL,
                                          __HIP_MEMORY_SCOPE_AGENT);
    is_last_s = (old == NBC - 1) ? 1 : 0;
    if (old == NBC - 1)
      __hip_atomic_store(&g_ticket, 0u, __ATOMIC_RELAXED,
                         __HIP_MEMORY_SCOPE_AGENT);   // reset for next launch
  }
  __syncthreads();

  if (is_last_s) {   // all 512 threads of the last block enter (barriers safe)
    if (t < 64) {
      feats_s[t] = __hip_atomic_load(&featsG[t], __ATOMIC_RELAXED,
                                     __HIP_MEMORY_SCOPE_AGENT);
      if (t < 32)
        feats_s[64 + t] = __hip_atomic_load(&featsG[64 + t], __ATOMIC_RELAXED,
                                            __HIP_MEMORY_SCOPE_AGENT);
      // Register-resident Gauss-Jordan: lane c<24 owns augmented column c.
      double M[12];
#pragma unroll
      for (int r = 0; r < 12; ++r) {
        double v = 0.0;
        if (t < 12) v = (double)cov_full[r * 36 + t];
        else if (t < 24) v = (t - 12 == r) ? 1.0 : 0.0;
        M[r] = v;
      }
#pragma unroll
      for (int k = 0; k < 12; ++k) {
        const double piv = __shfl(M[k], k);
        const double ip = 1.0 / piv;
        M[k] *= ip;
#pragma unroll
        for (int r = 0; r < 12; ++r) {
          if (r == k) continue;
          const double f = __shfl(M[r], k);   // old M[r][k]
          M[r] -= f * M[k];
        }
      }
      if (t >= 12 && t < 24) {
        const int j = t - 12;
#pragma unroll
        for (int r = 0; r < 12; ++r) inv_s[r][j] = M[r];
      }
    }
    __syncthreads();
    if (t < BATCH) {
      double acc2 = 0.0;
      double d[12];
#pragma unroll
      for (int i = 0; i < 12; ++i)
        d[i] = (double)feats_s[t * 12 + i] - (double)mu0_full[i];
#pragma unroll
      for (int i = 0; i < 12; ++i) {
        double row = 0.0;
#pragma unroll
        for (int j = 0; j < 12; ++j) row += inv_s[i][j] * d[j];
        acc2 += d[i] * row;
      }
      dist[t] = (float)sqrt(acc2);
    }
    __syncthreads();
    if (t == 0) {
      float m = 0.f;
#pragma unroll
      for (int b = 0; b < BATCH; ++b) m += dist[b];
      out[0] = m / (float)BATCH;
    }
  }
}

extern "C" void kernel_launch(void* const* d_in, const int* in_sizes, int n_in,
                              void* d_out, int out_size, void* d_ws, size_t ws_size,
                              hipStream_t stream) {
  const float* x   = (const float*)d_in[0];
  const float* mu0 = (const float*)d_in[1];
  const float* cov = (const float*)d_in[2];
  float* out = (float*)d_out;
  float* pf     = (float*)d_ws;                               // 32*44*132 floats = 743 KB
  float* featsG = pf + (size_t)NBC * NHB * NCHUNK * NSTAT;    // 96 floats

  band_stats_kernel<<<NBC * NHB, 320, 0, stream>>>(x, pf);
  patch_feats_kernel<<<NBC, 512, 0, stream>>>(pf, featsG, mu0, cov, out);
}